// Round 9
// baseline (274.730 us; speedup 1.0000x reference)
//
#include <hip/hip_runtime.h>
#include <hip/hip_fp16.h>
#include <cmath>

// Problem constants (fixed by setup_inputs): B=2, C=1, W=64, H=1024, d=32, WIN=32
#define H_DIM 1024
#define DCH 32
#define WINR 32
#define TQ 256
#define HALO (TQ + 2*WINR)      // 320 staged positions per tile
#define NBLK 512                // 128 rows * 4 tiles

__device__ __forceinline__ float gelu_f(float v) {
    return 0.5f * v * (1.0f + erff(v * 0.70710678118654752440f));
}

// fp16 rows: 4 uint4 chunks (8 halves each). Chunk XOR-swizzle spreads the
// (tiny) write phase across banks; broadcast reads are uniform -> conflict-free.
__device__ __forceinline__ int sxof(int p) { return (p & 3) ^ ((p >> 2) & 3); }

union H2U { unsigned u; __half2 h; };

__device__ __forceinline__ unsigned pack2(float a, float b) {
    H2U cv; cv.h = __floats2half2_rn(a, b); return cv.u;
}

// dot of one 8-half chunk with 8 fp32 q values (fp32 accumulate)
__device__ __forceinline__ float dot8(uint4 kc, const float* qp) {
    H2U a, b, c, d; a.u = kc.x; b.u = kc.y; c.u = kc.z; d.u = kc.w;
    float2 k0 = __half22float2(a.h), k1 = __half22float2(b.h);
    float2 k2 = __half22float2(c.h), k3 = __half22float2(d.h);
    float r = 0.f;
    r = fmaf(k0.x, qp[0], r); r = fmaf(k0.y, qp[1], r);
    r = fmaf(k1.x, qp[2], r); r = fmaf(k1.y, qp[3], r);
    r = fmaf(k2.x, qp[4], r); r = fmaf(k2.y, qp[5], r);
    r = fmaf(k3.x, qp[6], r); r = fmaf(k3.y, qp[7], r);
    return r;
}

// o8 += pw * V-chunk (8 halves)
__device__ __forceinline__ void pv8(uint4 vc, float pw, float* o8) {
    H2U a, b, c, d; a.u = vc.x; b.u = vc.y; c.u = vc.z; d.u = vc.w;
    float2 v0 = __half22float2(a.h), v1 = __half22float2(b.h);
    float2 v2 = __half22float2(c.h), v3 = __half22float2(d.h);
    o8[0] = fmaf(pw, v0.x, o8[0]); o8[1] = fmaf(pw, v0.y, o8[1]);
    o8[2] = fmaf(pw, v1.x, o8[2]); o8[3] = fmaf(pw, v1.y, o8[3]);
    o8[4] = fmaf(pw, v2.x, o8[4]); o8[5] = fmaf(pw, v2.y, o8[5]);
    o8[6] = fmaf(pw, v3.x, o8[6]); o8[7] = fmaf(pw, v3.y, o8[7]);
}

__device__ __forceinline__ void write_row_h(uint4* buf, int p, const float r[DCH]) {
    const int sx = sxof(p);
    #pragma unroll
    for (int c = 0; c < 4; ++c) {
        uint4 w;
        w.x = pack2(r[8*c+0], r[8*c+1]);
        w.y = pack2(r[8*c+2], r[8*c+3]);
        w.z = pack2(r[8*c+4], r[8*c+5]);
        w.w = pack2(r[8*c+6], r[8*c+7]);
        buf[p * 4 + (c ^ sx)] = w;
    }
}

__device__ __forceinline__ void matvec32(const float* __restrict__ w,
                                         const float zv[DCH], float out[DCH]) {
    #pragma unroll
    for (int e = 0; e < DCH; ++e) {
        const float* wr = w + e * DCH;
        float a0 = 0.f, a1 = 0.f, a2 = 0.f, a3 = 0.f;
        #pragma unroll
        for (int d = 0; d < DCH; d += 4) {
            a0 = fmaf(zv[d+0], wr[d+0], a0);
            a1 = fmaf(zv[d+1], wr[d+1], a1);
            a2 = fmaf(zv[d+2], wr[d+2], a2);
            a3 = fmaf(zv[d+3], wr[d+3], a3);
        }
        out[e] = (a0 + a1) + (a2 + a3);
    }
}

// ---------------------------------------------------------------- K1: x partial sums (GN1 stats; feat = x*w_in since C==1)
__global__ __launch_bounds__(256) void k_xstats(const float* __restrict__ x,
                                                double* __restrict__ part) { // [16][2]
    __shared__ double red[8];
    const int b = blockIdx.x;            // 16 blocks, 8 rows each
    const int t = threadIdx.x;
    const float4* px = (const float4*)(x + (size_t)b * 8192);
    double s = 0.0, s2 = 0.0;
    #pragma unroll
    for (int i = 0; i < 8; ++i) {
        float4 v = px[i * 256 + t];
        s  += (double)v.x + (double)v.y + (double)v.z + (double)v.w;
        s2 += (double)v.x*v.x + (double)v.y*v.y + (double)v.z*v.z + (double)v.w*v.w;
    }
    #pragma unroll
    for (int o = 32; o; o >>= 1) { s += __shfl_down(s, o); s2 += __shfl_down(s2, o); }
    if ((t & 63) == 0) { red[(t>>6)*2] = s; red[(t>>6)*2+1] = s2; }
    __syncthreads();
    if (t == 0) {
        part[b*2+0] = red[0]+red[2]+red[4]+red[6];
        part[b*2+1] = red[1]+red[3]+red[5]+red[7];
    }
}

// ---------------------------------------------------------------- K2: fused z->QKV->split-K banded attention->merge->residual
// 512 blocks x 512 threads. 8 waves: qq = wid&3 (query quarter), kh = wid>>2
// (key half). LDS 40KB -> 2 blocks/CU -> 4 waves/SIMD.
__global__ __launch_bounds__(512, 4) void k_main(
    const float* __restrict__ x,
    const float* __restrict__ w_in,
    const float* __restrict__ w_q,
    const float* __restrict__ w_k,
    const float* __restrict__ w_v,
    const float* __restrict__ gn_w,
    const float* __restrict__ gn_b,
    const float* __restrict__ gammap,
    const double* __restrict__ xpart,    // [16][2]
    double* __restrict__ gn2part,        // [512][2]
    float* __restrict__ out_pre)         // [128][1024][32]
{
    __shared__ uint4 kv[2][HALO * 4];    // [0]=K rows, [1]=V rows (fp16), 40 KB
    __shared__ double red[8];

    const int t     = threadIdx.x;
    const int lane  = t & 63;
    const int wid   = t >> 6;            // 0..7
    const int qq    = wid & 3;           // query quarter
    const int kh    = wid >> 2;          // key half
    const int bid   = blockIdx.x;
    const int row   = bid >> 2;
    const int tile  = bid & 3;
    const int batch = row >> 6;
    const int h0    = tile * TQ;
    const int g0    = h0 - WINR;

    // ---- GN1 stats from per-block x partials (uniform s_loads) ----
    double Sx = 0.0, Sx2 = 0.0;
    const double* bp = xpart + batch * 16;
    #pragma unroll
    for (int i = 0; i < 8; ++i) { Sx += bp[2*i]; Sx2 += bp[2*i+1]; }
    float sw = 0.f, sw2 = 0.f;
    #pragma unroll
    for (int d = 0; d < DCH; ++d) { float w = w_in[d]; sw += w; sw2 += w*w; }
    const double n1   = 2097152.0;                    // 32*64*1024
    const double mu1d = (double)sw * Sx / n1;
    const double var1 = (double)sw2 * Sx2 / n1 - mu1d * mu1d;
    const float  mu1  = (float)mu1d;
    const float  rstd1 = (float)(1.0 / sqrt(var1 + 1e-5));

    // z = gelu(x * ca[d] + cb[d])
    float ca[DCH], cb[DCH];
    #pragma unroll
    for (int d = 0; d < DCH; ++d) {
        float a = rstd1 * gn_w[d];
        ca[d] = w_in[d] * a;
        cb[d] = gn_b[d] - mu1 * a;
    }

    const float* xrow = x + (size_t)row * H_DIM;

    // ---- own-query z -> q (every thread; partner waves duplicate) ----
    const int qidx = qq * 64 + lane;     // query within tile
    const float xq = xrow[h0 + qidx];
    float q[DCH];
    {
        float zv[DCH];
        #pragma unroll
        for (int d = 0; d < DCH; ++d) zv[d] = gelu_f(fmaf(xq, ca[d], cb[d]));
        matvec32(w_q, zv, q);
        #pragma unroll
        for (int e = 0; e < DCH; ++e) q[e] *= 0.17677669529663688f; // 1/sqrt(32)
    }
    // ---- K/V staging: threads t<320 stage one halo row each ----
    if (t < HALO) {
        const int h  = g0 + t;
        const float xv = ((unsigned)h < H_DIM) ? xrow[h] : 0.f;
        float zv[DCH];
        #pragma unroll
        for (int d = 0; d < DCH; ++d) zv[d] = gelu_f(fmaf(xv, ca[d], cb[d]));
        float kr[DCH], vr[DCH];
        matvec32(w_k, zv, kr);
        matvec32(w_v, zv, vr);
        write_row_h(kv[0], t, kr);
        write_row_h(kv[1], t, vr);
    }
    __syncthreads();

    // ---- attention: this wave covers 64 of its queries' 128 key slots ----
    const int pbase = qq * 64 + kh * 64; // halo slot base for this wave

    float m = -80.0f, l = 0.f;
    float o[DCH];
    #pragma unroll
    for (int d = 0; d < DCH; ++d) o[d] = 0.f;

    #pragma unroll 2
    for (int ch = 0; ch < 8; ++ch) {
        float sc[8];
        // ---- score phase: 8 keys, branch-free ----
        #pragma unroll
        for (int u = 0; u < 8; ++u) {
            const int cu8 = ch * 8 + u;      // 0..63 within this wave's half
            const int p   = pbase + cu8;
            const int sx  = sxof(p);
            const uint4* kb = kv[0] + p * 4;
            uint4 c0 = kb[0 ^ sx];
            uint4 c1 = kb[1 ^ sx];
            uint4 c2 = kb[2 ^ sx];
            uint4 c3 = kb[3 ^ sx];
            const float s = (dot8(c0, q) + dot8(c1, q + 8)) +
                            (dot8(c2, q + 16) + dot8(c3, q + 24));
            const int rel = kh * 64 + cu8;   // slot relative to query block
            const bool valid = ((unsigned)(rel - lane) <= 64u) &&
                               ((unsigned)(g0 + p) < (unsigned)H_DIM);
            sc[u] = valid ? s : -3.0e38f;
        }
        // ---- chunk max tree ----
        const float c01 = fmaxf(sc[0], sc[1]);
        const float c23 = fmaxf(sc[2], sc[3]);
        const float c45 = fmaxf(sc[4], sc[5]);
        const float c67 = fmaxf(sc[6], sc[7]);
        const float cmax = fmaxf(fmaxf(c01, c23), fmaxf(c45, c67));
        // ---- one rescale vote per chunk (defer-max, THR=8) ----
        if (__any(cmax > m + 8.0f)) {
            const float mn = fmaxf(m, cmax);
            const float corr = __expf(m - mn);
            l *= corr;
            #pragma unroll
            for (int d = 0; d < DCH; ++d) o[d] *= corr;
            m = mn;
        }
        // ---- exp + PV phase ----
        #pragma unroll
        for (int u = 0; u < 8; ++u) {
            const float pw = __expf(sc[u] - m);  // 0 for invalid keys
            l += pw;
            const int p  = pbase + ch * 8 + u;
            const int sx = sxof(p);
            const uint4* vb = kv[1] + p * 4;
            pv8(vb[0 ^ sx], pw, o + 0);
            pv8(vb[1 ^ sx], pw, o + 8);
            pv8(vb[2 ^ sx], pw, o + 16);
            pv8(vb[3 ^ sx], pw, o + 24);
        }
    }

    // ---- split-K merge: kh=1 wave publishes (m,l,o); kh=0 merges ----
    __syncthreads();                      // all K/V reads complete
    float* mb = (float*)kv;               // 256 lanes x 35 floats = 35 KB <= 40 KB
    if (kh == 1) {
        float* dst = mb + (qq * 64 + lane) * 35;
        dst[0] = m; dst[1] = l;
        #pragma unroll
        for (int d = 0; d < DCH; ++d) dst[2 + d] = o[d];
    }
    __syncthreads();
    if (kh == 0) {
        const float* src = mb + (qq * 64 + lane) * 35;
        const float m2 = src[0], l2 = src[1];
        const float mm = fmaxf(m, m2);
        const float c1 = __expf(m - mm);
        const float c2 = __expf(m2 - mm);
        l = l * c1 + l2 * c2;
        #pragma unroll
        for (int d = 0; d < DCH; ++d) o[d] = o[d] * c1 + src[2 + d] * c2;

        const float inv = 1.0f / l;
        // ---- epilogue: out_pre = feat + gamma*o, GN2 partials ----
        const float gamma = gammap[0];
        float so = 0.f, so2 = 0.f;
        float* op = out_pre + ((size_t)row * H_DIM + (h0 + qidx)) * DCH;
        #pragma unroll
        for (int c = 0; c < 8; ++c) {
            float4 wi4 = ((const float4*)w_in)[c];
            float4 r;
            r.x = fmaf(gamma, o[4*c+0] * inv, xq * wi4.x);
            r.y = fmaf(gamma, o[4*c+1] * inv, xq * wi4.y);
            r.z = fmaf(gamma, o[4*c+2] * inv, xq * wi4.z);
            r.w = fmaf(gamma, o[4*c+3] * inv, xq * wi4.w);
            ((float4*)op)[c] = r;
            so  += r.x + r.y + r.z + r.w;
            so2 += r.x*r.x + r.y*r.y + r.z*r.z + r.w*r.w;
        }
        double ds = (double)so, ds2 = (double)so2;
        #pragma unroll
        for (int ofs = 32; ofs; ofs >>= 1) {
            ds  += __shfl_down(ds, ofs);
            ds2 += __shfl_down(ds2, ofs);
        }
        if (lane == 0) { red[qq*2] = ds; red[qq*2+1] = ds2; }
    }
    __syncthreads();
    if (t == 0) {
        gn2part[bid*2+0] = red[0]+red[2]+red[4]+red[6];
        gn2part[bid*2+1] = red[1]+red[3]+red[5]+red[7];
    }
}

// ---------------------------------------------------------------- K3: GN2 + gelu + out-projection
__global__ __launch_bounds__(256) void k_out(
    const float* __restrict__ out_pre,
    const float* __restrict__ w_out,
    const float* __restrict__ gn_w,
    const float* __restrict__ gn_b,
    const double* __restrict__ gn2part,  // [512][2]
    float* __restrict__ outp)
{
    __shared__ double red[8];
    const int t   = threadIdx.x;
    const int bid = blockIdx.x;
    const int batch = bid >> 8;          // uniform per block

    const double* gp = gn2part + (size_t)batch * 512;
    double ds = gp[2*t], ds2 = gp[2*t+1];
    #pragma unroll
    for (int ofs = 32; ofs; ofs >>= 1) {
        ds  += __shfl_down(ds, ofs);
        ds2 += __shfl_down(ds2, ofs);
    }
    if ((t & 63) == 0) { red[(t>>6)*2] = ds; red[(t>>6)*2+1] = ds2; }
    __syncthreads();
    const double S  = red[0]+red[2]+red[4]+red[6];
    const double S2 = red[1]+red[3]+red[5]+red[7];
    const double n2 = 2097152.0;
    const double mu = S / n2;
    const double var = S2 / n2 - mu * mu;
    const float muf  = (float)mu;
    const float rstd = (float)(1.0 / sqrt(var + 1e-5));

    const int pix = bid * 256 + t;
    const float4* ip = (const float4*)(out_pre + (size_t)pix * DCH);
    float acc_o = 0.f;
    #pragma unroll
    for (int c = 0; c < 8; ++c) {
        float4 v  = ip[c];
        float4 gw = ((const float4*)gn_w)[c];
        float4 gb = ((const float4*)gn_b)[c];
        float4 wo = ((const float4*)w_out)[c];
        acc_o += gelu_f((v.x - muf) * rstd * gw.x + gb.x) * wo.x;
        acc_o += gelu_f((v.y - muf) * rstd * gw.y + gb.y) * wo.y;
        acc_o += gelu_f((v.z - muf) * rstd * gw.z + gb.z) * wo.z;
        acc_o += gelu_f((v.w - muf) * rstd * gw.w + gb.w) * wo.w;
    }
    outp[pix] = acc_o;
}

// ---------------------------------------------------------------- launch
extern "C" void kernel_launch(void* const* d_in, const int* in_sizes, int n_in,
                              void* d_out, int out_size, void* d_ws, size_t ws_size,
                              hipStream_t stream) {
    const float* x     = (const float*)d_in[0];
    const float* w_in  = (const float*)d_in[1];
    const float* w_q   = (const float*)d_in[2];
    const float* w_k   = (const float*)d_in[3];
    const float* w_v   = (const float*)d_in[4];
    const float* w_out = (const float*)d_in[5];
    const float* gn_w  = (const float*)d_in[6];
    const float* gn_b  = (const float*)d_in[7];
    const float* gamma = (const float*)d_in[8];

    double* xpart   = (double*)d_ws;                          // 32 doubles
    double* gn2part = (double*)((char*)d_ws + 256);           // 1024 doubles
    float*  out_pre = (float*)((char*)d_ws + 8448);           // 16.78 MB
    float*  outp    = (float*)d_out;

    k_xstats<<<dim3(16),   dim3(256), 0, stream>>>(x, xpart);
    k_main  <<<dim3(NBLK), dim3(512), 0, stream>>>(
        x, w_in, w_q, w_k, w_v, gn_w, gn_b, gamma, xpart, gn2part, out_pre);
    k_out   <<<dim3(512),  dim3(256), 0, stream>>>(out_pre, w_out, gn_w, gn_b, gn2part, outp);
}

// Round 10
// 207.107 us; speedup vs baseline: 1.3265x; 1.3265x over previous
//
#include <hip/hip_runtime.h>
#include <hip/hip_fp16.h>
#include <cmath>

// Problem constants: B=2, C=1, W=64, H=1024, d=32, WIN=32
#define H_DIM 1024
#define DCH 32
#define WINR 32
#define TQ 256
#define NQ 131072               // total queries = 128*1024
#define NBT 512                 // (row,tile) pairs

__device__ __forceinline__ float gelu_f(float v) {
    return 0.5f * v * (1.0f + erff(v * 0.70710678118654752440f));
}

// fp16 rows: 4 uint4 chunks (8 halves each); chunk XOR-swizzle for the write phase
__device__ __forceinline__ int sxof(int p) { return (p & 3) ^ ((p >> 2) & 3); }

union H2U { unsigned u; __half2 h; };

__device__ __forceinline__ unsigned pack2(float a, float b) {
    H2U cv; cv.h = __floats2half2_rn(a, b); return cv.u;
}

__device__ __forceinline__ float dot8(uint4 kc, const float* qp) {
    H2U a, b, c, d; a.u = kc.x; b.u = kc.y; c.u = kc.z; d.u = kc.w;
    float2 k0 = __half22float2(a.h), k1 = __half22float2(b.h);
    float2 k2 = __half22float2(c.h), k3 = __half22float2(d.h);
    float r = 0.f;
    r = fmaf(k0.x, qp[0], r); r = fmaf(k0.y, qp[1], r);
    r = fmaf(k1.x, qp[2], r); r = fmaf(k1.y, qp[3], r);
    r = fmaf(k2.x, qp[4], r); r = fmaf(k2.y, qp[5], r);
    r = fmaf(k3.x, qp[6], r); r = fmaf(k3.y, qp[7], r);
    return r;
}

__device__ __forceinline__ void pv8(uint4 vc, float pw, float* o8) {
    H2U a, b, c, d; a.u = vc.x; b.u = vc.y; c.u = vc.z; d.u = vc.w;
    float2 v0 = __half22float2(a.h), v1 = __half22float2(b.h);
    float2 v2 = __half22float2(c.h), v3 = __half22float2(d.h);
    o8[0] = fmaf(pw, v0.x, o8[0]); o8[1] = fmaf(pw, v0.y, o8[1]);
    o8[2] = fmaf(pw, v1.x, o8[2]); o8[3] = fmaf(pw, v1.y, o8[3]);
    o8[4] = fmaf(pw, v2.x, o8[4]); o8[5] = fmaf(pw, v2.y, o8[5]);
    o8[6] = fmaf(pw, v3.x, o8[6]); o8[7] = fmaf(pw, v3.y, o8[7]);
}

__device__ __forceinline__ void write_row_h(uint4* buf, int p, const float r[DCH]) {
    const int sx = sxof(p);
    #pragma unroll
    for (int c = 0; c < 4; ++c) {
        uint4 w;
        w.x = pack2(r[8*c+0], r[8*c+1]);
        w.y = pack2(r[8*c+2], r[8*c+3]);
        w.z = pack2(r[8*c+4], r[8*c+5]);
        w.w = pack2(r[8*c+6], r[8*c+7]);
        buf[p * 4 + (c ^ sx)] = w;
    }
}

__device__ __forceinline__ void matvec32(const float* __restrict__ w,
                                         const float zv[DCH], float out[DCH]) {
    #pragma unroll
    for (int e = 0; e < DCH; ++e) {
        const float* wr = w + e * DCH;
        float a0 = 0.f, a1 = 0.f, a2 = 0.f, a3 = 0.f;
        #pragma unroll
        for (int d = 0; d < DCH; d += 4) {
            a0 = fmaf(zv[d+0], wr[d+0], a0);
            a1 = fmaf(zv[d+1], wr[d+1], a1);
            a2 = fmaf(zv[d+2], wr[d+2], a2);
            a3 = fmaf(zv[d+3], wr[d+3], a3);
        }
        out[e] = (a0 + a1) + (a2 + a3);
    }
}

// ---------------------------------------------------------------- K1: x partial sums (GN1 stats)
__global__ __launch_bounds__(256) void k_xstats(const float* __restrict__ x,
                                                double* __restrict__ part) { // [16][2]
    __shared__ double red[8];
    const int b = blockIdx.x;
    const int t = threadIdx.x;
    const float4* px = (const float4*)(x + (size_t)b * 8192);
    double s = 0.0, s2 = 0.0;
    #pragma unroll
    for (int i = 0; i < 8; ++i) {
        float4 v = px[i * 256 + t];
        s  += (double)v.x + (double)v.y + (double)v.z + (double)v.w;
        s2 += (double)v.x*v.x + (double)v.y*v.y + (double)v.z*v.z + (double)v.w*v.w;
    }
    #pragma unroll
    for (int o = 32; o; o >>= 1) { s += __shfl_down(s, o); s2 += __shfl_down(s2, o); }
    if ((t & 63) == 0) { red[(t>>6)*2] = s; red[(t>>6)*2+1] = s2; }
    __syncthreads();
    if (t == 0) {
        part[b*2+0] = red[0]+red[2]+red[4]+red[6];
        part[b*2+1] = red[1]+red[3]+red[5]+red[7];
    }
}

// ---------------------------------------------------------------- K2: split-K half-attention -> partials
// 1024 blocks (bt = bid>>1 in [0,512), kh = bid&1), 256 threads. LDS 32 KB.
// Each block covers, for every query t of its tile, key offsets:
//   kh=0: j in [lane,64)  -> offsets [-32, 31-lane]
//   kh=1: j in [0,lane]   -> offsets [32-lane, 32]   (disjoint union = 65 keys)
__global__ __launch_bounds__(256, 4) void k_main(
    const float* __restrict__ x,
    const float* __restrict__ w_in,
    const float* __restrict__ w_q,
    const float* __restrict__ w_k,
    const float* __restrict__ w_v,
    const float* __restrict__ gn_w,
    const float* __restrict__ gn_b,
    const double* __restrict__ xpart,    // [16][2]
    float* __restrict__ Mpart,           // [2][NQ]
    float* __restrict__ Lpart,           // [2][NQ]
    uint4* __restrict__ Opart)           // [2][4][NQ] fp16 chunks
{
    __shared__ uint4 kv[2][TQ * 4];      // [0]=K, [1]=V (fp16 rows), 32 KB

    const int t     = threadIdx.x;
    const int lane  = t & 63;
    const int wid   = t >> 6;
    const int bid   = blockIdx.x;
    const int kh    = bid & 1;
    const int bt    = bid >> 1;          // row*4 + tile
    const int row   = bt >> 2;
    const int tile  = bt & 3;
    const int batch = row >> 6;
    const int h0    = tile * TQ;
    const int g0    = h0 - WINR;

    // ---- GN1 stats from x partials ----
    double Sx = 0.0, Sx2 = 0.0;
    const double* bp = xpart + batch * 16;
    #pragma unroll
    for (int i = 0; i < 8; ++i) { Sx += bp[2*i]; Sx2 += bp[2*i+1]; }
    float sw = 0.f, sw2 = 0.f;
    #pragma unroll
    for (int d = 0; d < DCH; ++d) { float w = w_in[d]; sw += w; sw2 += w*w; }
    const double n1   = 2097152.0;
    const double mu1d = (double)sw * Sx / n1;
    const double var1 = (double)sw2 * Sx2 / n1 - mu1d * mu1d;
    const float  mu1  = (float)mu1d;
    const float  rstd1 = (float)(1.0 / sqrt(var1 + 1e-5));

    float ca[DCH], cb[DCH];
    #pragma unroll
    for (int d = 0; d < DCH; ++d) {
        float a = rstd1 * gn_w[d];
        ca[d] = w_in[d] * a;
        cb[d] = gn_b[d] - mu1 * a;
    }

    const float* xrow = x + (size_t)row * H_DIM;

    // ---- stage K/V: thread t stages local row t (global h = g0 + kh*64 + t) ----
    {
        const int hst = g0 + kh * 64 + t;
        const float xv = ((unsigned)hst < H_DIM) ? xrow[hst] : 0.f;
        float zv[DCH];
        #pragma unroll
        for (int d = 0; d < DCH; ++d) zv[d] = gelu_f(fmaf(xv, ca[d], cb[d]));
        float kr[DCH], vr[DCH];
        matvec32(w_k, zv, kr);
        matvec32(w_v, zv, vr);
        write_row_h(kv[0], t, kr);
        write_row_h(kv[1], t, vr);
    }
    // ---- own-query q ----
    const float xq = xrow[h0 + t];
    float q[DCH];
    {
        float zv[DCH];
        #pragma unroll
        for (int d = 0; d < DCH; ++d) zv[d] = gelu_f(fmaf(xq, ca[d], cb[d]));
        matvec32(w_q, zv, q);
        #pragma unroll
        for (int e = 0; e < DCH; ++e) q[e] *= 0.17677669529663688f;
    }
    __syncthreads();

    // ---- half attention: 64 keys (8 chunks), broadcast reads ----
    const int jmin = kh ? 0 : lane;
    const int jmax = kh ? lane : 63;
    const int hb   = g0 + kh * 64 + wid * 64;   // global h of local row wid*64

    float m = -80.0f, l = 0.f;
    float o[DCH];
    #pragma unroll
    for (int d = 0; d < DCH; ++d) o[d] = 0.f;

    #pragma unroll 2
    for (int ch = 0; ch < 8; ++ch) {
        float sc[8];
        #pragma unroll
        for (int u = 0; u < 8; ++u) {
            const int j = ch * 8 + u;
            const int r = wid * 64 + j;          // local LDS row (wave-uniform)
            const int sx = sxof(r);
            const uint4* kb = kv[0] + r * 4;
            uint4 c0 = kb[0 ^ sx];
            uint4 c1 = kb[1 ^ sx];
            uint4 c2 = kb[2 ^ sx];
            uint4 c3 = kb[3 ^ sx];
            const float s = (dot8(c0, q) + dot8(c1, q + 8)) +
                            (dot8(c2, q + 16) + dot8(c3, q + 24));
            const bool valid = (j >= jmin) && (j <= jmax) &&
                               ((unsigned)(hb + j) < (unsigned)H_DIM);
            sc[u] = valid ? s : -3.0e38f;
        }
        const float c01 = fmaxf(sc[0], sc[1]);
        const float c23 = fmaxf(sc[2], sc[3]);
        const float c45 = fmaxf(sc[4], sc[5]);
        const float c67 = fmaxf(sc[6], sc[7]);
        const float cmax = fmaxf(fmaxf(c01, c23), fmaxf(c45, c67));
        if (__any(cmax > m + 8.0f)) {            // defer-max, THR=8
            const float mn = fmaxf(m, cmax);
            const float corr = __expf(m - mn);
            l *= corr;
            #pragma unroll
            for (int d = 0; d < DCH; ++d) o[d] *= corr;
            m = mn;
        }
        #pragma unroll
        for (int u = 0; u < 8; ++u) {
            const float pw = __expf(sc[u] - m);
            l += pw;
            const int r  = wid * 64 + ch * 8 + u;
            const int sx = sxof(r);
            const uint4* vb = kv[1] + r * 4;
            pv8(vb[0 ^ sx], pw, o + 0);
            pv8(vb[1 ^ sx], pw, o + 8);
            pv8(vb[2 ^ sx], pw, o + 16);
            pv8(vb[3 ^ sx], pw, o + 24);
        }
    }

    // ---- write partials (coalesced, chunk-major) ----
    const int qg = bt * 256 + t;
    Mpart[kh * NQ + qg] = m;
    Lpart[kh * NQ + qg] = l;
    #pragma unroll
    for (int c = 0; c < 4; ++c) {
        uint4 w;
        w.x = pack2(o[8*c+0], o[8*c+1]);
        w.y = pack2(o[8*c+2], o[8*c+3]);
        w.z = pack2(o[8*c+4], o[8*c+5]);
        w.w = pack2(o[8*c+6], o[8*c+7]);
        Opart[(size_t)(kh * 4 + c) * NQ + qg] = w;
    }
}

// ---------------------------------------------------------------- K3: merge halves + epilogue + GN2 partials
__global__ __launch_bounds__(256) void k_merge(
    const float* __restrict__ x,
    const float* __restrict__ w_in,
    const float* __restrict__ gammap,
    const float* __restrict__ Mpart,
    const float* __restrict__ Lpart,
    const uint4* __restrict__ Opart,
    double* __restrict__ gn2part,        // [512][2]
    float* __restrict__ out_pre)
{
    __shared__ double red[8];
    const int t   = threadIdx.x;
    const int bid = blockIdx.x;          // == bt
    const int row = bid >> 2;
    const int hq  = (bid & 3) * TQ + t;
    const int qg  = bid * 256 + t;

    const float xq = x[(size_t)row * H_DIM + hq];
    const float m1 = Mpart[qg],      m2 = Mpart[NQ + qg];
    const float l1 = Lpart[qg],      l2 = Lpart[NQ + qg];
    const float mm = fmaxf(m1, m2);
    const float c1 = __expf(m1 - mm);
    const float c2 = __expf(m2 - mm);
    const float inv = 1.0f / (l1 * c1 + l2 * c2);
    const float gamma = gammap[0];
    const float g1 = gamma * c1 * inv;
    const float g2 = gamma * c2 * inv;

    float so = 0.f, so2 = 0.f;
    float* op = out_pre + (size_t)qg * DCH;
    #pragma unroll
    for (int c = 0; c < 4; ++c) {
        uint4 a = Opart[(size_t)c * NQ + qg];
        uint4 b = Opart[(size_t)(4 + c) * NQ + qg];
        H2U ua0, ua1, ua2, ua3, ub0, ub1, ub2, ub3;
        ua0.u = a.x; ua1.u = a.y; ua2.u = a.z; ua3.u = a.w;
        ub0.u = b.x; ub1.u = b.y; ub2.u = b.z; ub3.u = b.w;
        float2 a0 = __half22float2(ua0.h), a1 = __half22float2(ua1.h);
        float2 a2 = __half22float2(ua2.h), a3 = __half22float2(ua3.h);
        float2 b0 = __half22float2(ub0.h), b1 = __half22float2(ub1.h);
        float2 b2 = __half22float2(ub2.h), b3 = __half22float2(ub3.h);
        float4 wi0 = ((const float4*)w_in)[2*c];
        float4 wi1 = ((const float4*)w_in)[2*c+1];
        float4 r0, r1;
        r0.x = fmaf(a0.x, g1, b0.x * g2) + xq * wi0.x;
        r0.y = fmaf(a0.y, g1, b0.y * g2) + xq * wi0.y;
        r0.z = fmaf(a1.x, g1, b1.x * g2) + xq * wi0.z;
        r0.w = fmaf(a1.y, g1, b1.y * g2) + xq * wi0.w;
        r1.x = fmaf(a2.x, g1, b2.x * g2) + xq * wi1.x;
        r1.y = fmaf(a2.y, g1, b2.y * g2) + xq * wi1.y;
        r1.z = fmaf(a3.x, g1, b3.x * g2) + xq * wi1.z;
        r1.w = fmaf(a3.y, g1, b3.y * g2) + xq * wi1.w;
        ((float4*)op)[2*c]   = r0;
        ((float4*)op)[2*c+1] = r1;
        so  += r0.x + r0.y + r0.z + r0.w + r1.x + r1.y + r1.z + r1.w;
        so2 += r0.x*r0.x + r0.y*r0.y + r0.z*r0.z + r0.w*r0.w
             + r1.x*r1.x + r1.y*r1.y + r1.z*r1.z + r1.w*r1.w;
    }
    double ds = (double)so, ds2 = (double)so2;
    #pragma unroll
    for (int ofs = 32; ofs; ofs >>= 1) {
        ds  += __shfl_down(ds, ofs);
        ds2 += __shfl_down(ds2, ofs);
    }
    if ((t & 63) == 0) { red[(t>>6)*2] = ds; red[(t>>6)*2+1] = ds2; }
    __syncthreads();
    if (t == 0) {
        gn2part[bid*2+0] = red[0]+red[2]+red[4]+red[6];
        gn2part[bid*2+1] = red[1]+red[3]+red[5]+red[7];
    }
}

// ---------------------------------------------------------------- K4: GN2 + gelu + out-projection
__global__ __launch_bounds__(256) void k_out(
    const float* __restrict__ out_pre,
    const float* __restrict__ w_out,
    const float* __restrict__ gn_w,
    const float* __restrict__ gn_b,
    const double* __restrict__ gn2part,  // [512][2]
    float* __restrict__ outp)
{
    __shared__ double red[8];
    const int t   = threadIdx.x;
    const int bid = blockIdx.x;
    const int batch = bid >> 8;

    const double* gp = gn2part + (size_t)batch * 512;
    double ds = gp[2*t], ds2 = gp[2*t+1];
    #pragma unroll
    for (int ofs = 32; ofs; ofs >>= 1) {
        ds  += __shfl_down(ds, ofs);
        ds2 += __shfl_down(ds2, ofs);
    }
    if ((t & 63) == 0) { red[(t>>6)*2] = ds; red[(t>>6)*2+1] = ds2; }
    __syncthreads();
    const double S  = red[0]+red[2]+red[4]+red[6];
    const double S2 = red[1]+red[3]+red[5]+red[7];
    const double n2 = 2097152.0;
    const double mu = S / n2;
    const double var = S2 / n2 - mu * mu;
    const float muf  = (float)mu;
    const float rstd = (float)(1.0 / sqrt(var + 1e-5));

    const int pix = bid * 256 + t;
    const float4* ip = (const float4*)(out_pre + (size_t)pix * DCH);
    float acc_o = 0.f;
    #pragma unroll
    for (int c = 0; c < 8; ++c) {
        float4 v  = ip[c];
        float4 gw = ((const float4*)gn_w)[c];
        float4 gb = ((const float4*)gn_b)[c];
        float4 wo = ((const float4*)w_out)[c];
        acc_o += gelu_f((v.x - muf) * rstd * gw.x + gb.x) * wo.x;
        acc_o += gelu_f((v.y - muf) * rstd * gw.y + gb.y) * wo.y;
        acc_o += gelu_f((v.z - muf) * rstd * gw.z + gb.z) * wo.z;
        acc_o += gelu_f((v.w - muf) * rstd * gw.w + gb.w) * wo.w;
    }
    outp[pix] = acc_o;
}

// ---------------------------------------------------------------- launch
extern "C" void kernel_launch(void* const* d_in, const int* in_sizes, int n_in,
                              void* d_out, int out_size, void* d_ws, size_t ws_size,
                              hipStream_t stream) {
    const float* x     = (const float*)d_in[0];
    const float* w_in  = (const float*)d_in[1];
    const float* w_q   = (const float*)d_in[2];
    const float* w_k   = (const float*)d_in[3];
    const float* w_v   = (const float*)d_in[4];
    const float* w_out = (const float*)d_in[5];
    const float* gn_w  = (const float*)d_in[6];
    const float* gn_b  = (const float*)d_in[7];
    const float* gamma = (const float*)d_in[8];

    char* ws = (char*)d_ws;
    double* xpart   = (double*)ws;                            // 256 B
    double* gn2part = (double*)(ws + 256);                    // 8 KB -> 8448
    float*  out_pre = (float*)(ws + 8448);                    // 16.78 MB -> 16,785,664
    float*  Mpart   = (float*)(ws + 16785664);                // 1.05 MB -> 17,834,240
    float*  Lpart   = (float*)(ws + 17834240);                // 1.05 MB -> 18,882,816
    uint4*  Opart   = (uint4*)(ws + 18882816);                // 16.78 MB -> 35,660,032
    float*  outp    = (float*)d_out;

    k_xstats<<<dim3(16),   dim3(256), 0, stream>>>(x, xpart);
    k_main  <<<dim3(1024), dim3(256), 0, stream>>>(
        x, w_in, w_q, w_k, w_v, gn_w, gn_b, xpart, Mpart, Lpart, Opart);
    k_merge <<<dim3(512),  dim3(256), 0, stream>>>(
        x, w_in, gamma, Mpart, Lpart, Opart, gn2part, out_pre);
    k_out   <<<dim3(512),  dim3(256), 0, stream>>>(out_pre, w_out, gn_w, gn_b, gn2part, outp);
}